// Round 7
// baseline (179.008 us; speedup 1.0000x reference)
//
#include <hip/hip_runtime.h>

typedef __bf16 bf16_t;
typedef __bf16 bf16x8 __attribute__((ext_vector_type(8)));
typedef __bf16 bf16x4 __attribute__((ext_vector_type(4)));
typedef float  f32x4  __attribute__((ext_vector_type(4)));

#define B_DIM 4
#define S_DIM 4096
#define D_DIM 1024
#define M_DIM (B_DIM * S_DIM)   // 16384 rows

#define CHUNK 64   // scan output steps per block
#define WARM  24   // scan warm-up steps

__device__ __forceinline__ void g2l16(const void* g, void* l) {
  __builtin_amdgcn_global_load_lds(
      (const __attribute__((address_space(1))) void*)g,
      (__attribute__((address_space(3))) void*)l, 16, 0, 0);
}

// ---------------- LayerNorm fp32 -> bf16, one wave per row ----------------
__global__ __launch_bounds__(64) void ln_kernel(
    const float* __restrict__ x, const float* __restrict__ gamma,
    const float* __restrict__ beta, bf16_t* __restrict__ h) {
  const int row  = blockIdx.x;
  const int lane = threadIdx.x;
  const float4* xr = (const float4*)(x + (size_t)row * D_DIM);
  float4 v[4];
  float s = 0.f, s2 = 0.f;
#pragma unroll
  for (int j = 0; j < 4; ++j) {
    v[j] = xr[j * 64 + lane];
    s += v[j].x + v[j].y + v[j].z + v[j].w;
    s2 = fmaf(v[j].x, v[j].x, s2);
    s2 = fmaf(v[j].y, v[j].y, s2);
    s2 = fmaf(v[j].z, v[j].z, s2);
    s2 = fmaf(v[j].w, v[j].w, s2);
  }
#pragma unroll
  for (int off = 32; off; off >>= 1) {
    s  += __shfl_xor(s, off);
    s2 += __shfl_xor(s2, off);
  }
  const float mu  = s * (1.f / (float)D_DIM);
  const float var = fmaf(-mu, mu, s2 * (1.f / (float)D_DIM));
  const float inv = rsqrtf(var + 1e-5f);
  bf16_t* hr = h + (size_t)row * D_DIM;
#pragma unroll
  for (int j = 0; j < 4; ++j) {
    const float4 g4 = ((const float4*)gamma)[j * 64 + lane];
    const float4 b4 = ((const float4*)beta)[j * 64 + lane];
    bf16x4 o;
    o[0] = (bf16_t)fmaf((v[j].x - mu) * inv, g4.x, b4.x);
    o[1] = (bf16_t)fmaf((v[j].y - mu) * inv, g4.y, b4.y);
    o[2] = (bf16_t)fmaf((v[j].z - mu) * inv, g4.z, b4.z);
    o[3] = (bf16_t)fmaf((v[j].w - mu) * inv, g4.w, b4.w);
    ((bf16x4*)hr)[j * 64 + lane] = o;
  }
}

// ------------- W [K][N] fp32  ->  WT [N][K] bf16 (tiled transpose) --------
__global__ __launch_bounds__(256) void transpose_kernel(
    const float* __restrict__ W, bf16_t* __restrict__ WT) {
  __shared__ float tile[32][33];
  const int tx = threadIdx.x & 31;
  const int ty = threadIdx.x >> 5;
  const int bn = blockIdx.x * 32;
  const int bk = blockIdx.y * 32;
#pragma unroll
  for (int i = 0; i < 32; i += 8)
    tile[ty + i][tx] = W[(size_t)(bk + ty + i) * D_DIM + bn + tx];
  __syncthreads();
#pragma unroll
  for (int i = 0; i < 32; i += 8)
    WT[(size_t)(bn + ty + i) * D_DIM + bk + tx] = (bf16_t)tile[tx][ty + i];
}

// == bf16 NT GEMM, 256x256 tile, reg-dbuf fragments, cross-step overlap ====
// C[M][N] = A[M][K] * BT[N][K]^T ; MODE 0: bf16(acc+bias); MODE 1: f32 +x
// Ring-3 LDS, 32KB/buf: A [256 rows][64B] @0 | B [256 rows][64B] @16384.
// (row,k) at 16B slot (k>>3)^((row>>1)&3)  [measured 0-conflict].
// Step t: stage(t+2); vmcnt(4); barrier; issue 12 ds_reads for frags(t+1);
//         lgkmcnt(12) [frags(t) done, frags(t+1) IN FLIGHT]; MFMA on frags(t).
#define NTK 32        // K / 32

#define VMCNT(n) asm volatile("s_waitcnt vmcnt(" #n ")" ::: "memory")
#define LGKM(n)  asm volatile("s_waitcnt lgkmcnt(" #n ")" ::: "memory")
#define BARRIER()                      \
  {                                    \
    asm volatile("" ::: "memory");     \
    __builtin_amdgcn_s_barrier();      \
    asm volatile("" ::: "memory");     \
  }
#define DSR(d, a, off) \
  asm volatile("ds_read_b128 %0, %1 offset:" #off : "=v"(d) : "v"(a))

template <int MODE>
__global__ __launch_bounds__(512, 2) void gemm_nt_kernel(
    const bf16_t* __restrict__ A, const bf16_t* __restrict__ BT,
    const float* __restrict__ bias, const float* __restrict__ xres,
    void* __restrict__ Cout) {
  __shared__ __attribute__((aligned(16))) char lds[3][32768];
  char* ldsbase = (char*)lds;
  const int tid  = threadIdx.x;
  const int lane = tid & 63;
  const int wave = tid >> 6;           // 0..7
  const int wr = wave >> 2;            // 0..1 (M half: 128 rows)
  const int wc = wave & 3;             // 0..3 (N quarter: 64 cols)
  const int bid = blockIdx.x;
  const int swz = (bid & 7) * 32 + (bid >> 3);   // 256 blocks, 8 XCDs
  const int m0 = (swz >> 2) * 256;
  const int n0 = (swz & 3) * 256;

  // convoy-breaking start stagger
  const int dly = (int)((bid * 2654435761u) >> 29);
  for (int i = 0; i < dly; ++i) __builtin_amdgcn_s_sleep(1);

  // staging: thread covers (row = tid>>2, phys slot = tid&3); source k-elems
  // start at ((tid&3) ^ ((row>>1)&3))*8
  const int ke = (((tid & 3) ^ ((tid >> 3) & 3)) << 3);
  const bf16_t* srcA = A  + (size_t)(m0 + (tid >> 2)) * D_DIM + ke;
  const bf16_t* srcB = BT + (size_t)(n0 + (tid >> 2)) * D_DIM + ke;
  const int l16 = tid * 16;

  // fragment read bases (asm 32-bit LDS addresses)
  const uint32_t lbase = (uint32_t)(uintptr_t)&lds[0][0];
  const int sw   = (((lane >> 4) ^ ((lane >> 1) & 3)) << 4);
  const uint32_t aRd = lbase + (uint32_t)((wr * 128 + (lane & 15)) * 64 + sw);
  const uint32_t bRd = lbase + 16384u +
                       (uint32_t)((wc * 64 + (lane & 15)) * 64 + sw);

  f32x4 acc[8][4];
#pragma unroll
  for (int m = 0; m < 8; ++m)
#pragma unroll
    for (int n = 0; n < 4; ++n) acc[m][n] = (f32x4){0.f, 0.f, 0.f, 0.f};

#define STAGE(T, BOFF)                                       \
  {                                                          \
    char* dst = ldsbase + (BOFF) + l16;                      \
    const size_t ko = (size_t)(T) * 32;                      \
    g2l16(srcA + ko, dst);                                   \
    g2l16(srcA + (size_t)128 * D_DIM + ko, dst + 8192);      \
    g2l16(srcB + ko, dst + 16384);                           \
    g2l16(srcB + (size_t)128 * D_DIM + ko, dst + 24576);     \
  }

#define DSR12(NA, NB, O1)                       \
  {                                             \
    const uint32_t aA_ = aRd + (O1);            \
    const uint32_t bA_ = bRd + (O1);            \
    DSR(NA[0], aA_, 0);                         \
    DSR(NA[1], aA_, 1024);                      \
    DSR(NA[2], aA_, 2048);                      \
    DSR(NA[3], aA_, 3072);                      \
    DSR(NA[4], aA_, 4096);                      \
    DSR(NA[5], aA_, 5120);                      \
    DSR(NA[6], aA_, 6144);                      \
    DSR(NA[7], aA_, 7168);                      \
    DSR(NB[0], bA_, 0);                         \
    DSR(NB[1], bA_, 1024);                      \
    DSR(NB[2], bA_, 2048);                      \
    DSR(NB[3], bA_, 3072);                      \
  }

#define MFMA32(CA, CB)                                                      \
  _Pragma("unroll") for (int mm = 0; mm < 8; ++mm)                          \
      _Pragma("unroll") for (int nn = 0; nn < 4; ++nn)                      \
          acc[mm][nn] = __builtin_amdgcn_mfma_f32_16x16x32_bf16(            \
              CA[mm], CB[nn], acc[mm][nn], 0, 0, 0);

#define STEP(CA, CB, NA, NB, T)                                   \
  {                                                               \
    if ((T) + 2 < NTK) STAGE((T) + 2, o2);                        \
    if ((T) < NTK - 2) { VMCNT(4); } else { VMCNT(0); }           \
    BARRIER();                                                    \
    if ((T) + 1 < NTK) { DSR12(NA, NB, o1); LGKM(12); }           \
    else { LGKM(0); }                                             \
    __builtin_amdgcn_sched_barrier(0);                            \
    __builtin_amdgcn_s_setprio(1);                                \
    MFMA32(CA, CB);                                               \
    __builtin_amdgcn_s_setprio(0);                                \
    { const uint32_t t_ = o1; o1 = o2;                            \
      o2 = (t_ == 0u ? 65536u : t_ - 32768u); }                   \
  }

  bf16x8 a0[8], b0[4], a1[8], b1[4];

  // prologue: stage tiles 0,1; read frags0 into set0
  STAGE(0, 0u);
  STAGE(1, 32768u);
  VMCNT(4);           // stage0 landed (stage1 in flight)
  BARRIER();
  DSR12(a0, b0, 0u);
  uint32_t o1 = 32768u, o2 = 65536u;

  for (int t2 = 0; t2 < NTK; t2 += 2) {
    STEP(a0, b0, a1, b1, t2);
    STEP(a1, b1, a0, b0, t2 + 1);
  }

#undef STEP
#undef MFMA32
#undef DSR12
#undef STAGE

  // epilogue: C/D layout col = lane&15, row = (lane>>4)*4 + r
  const int rbase = m0 + wr * 128 + ((lane >> 4) << 2);
  const int cbase = n0 + wc * 64 + (lane & 15);
#pragma unroll
  for (int n = 0; n < 4; ++n) {
    const int col = cbase + n * 16;
    const float bn = bias[col];
#pragma unroll
    for (int m = 0; m < 8; ++m) {
      const int row = rbase + m * 16;
#pragma unroll
      for (int r = 0; r < 4; ++r) {
        const size_t idx = (size_t)(row + r) * D_DIM + col;
        if (MODE == 0)
          ((bf16_t*)Cout)[idx] = (bf16_t)(acc[m][n][r] + bn);
        else
          ((float*)Cout)[idx] = xres[idx] + acc[m][n][r] + bn;
      }
    }
  }
}

// ---------------- chunked chaotic scan, one wave per (batch, chunk) -------
__global__ __launch_bounds__(64) void scan_kernel(
    const bf16_t* __restrict__ c, bf16_t* __restrict__ y) {
  const int b     = blockIdx.y;
  const int chunk = blockIdx.x;
  const int t0    = chunk * CHUNK;
  const int start = (chunk == 0) ? 0 : t0 - WARM;
  const int tend  = t0 + CHUNK;
  const int lane  = threadIdx.x;

  float zre[8], zim[8];
#pragma unroll
  for (int j = 0; j < 8; ++j) { zre[j] = 0.f; zim[j] = 0.f; }

  const bf16_t* crow = c + ((size_t)b * S_DIM + start) * D_DIM;
  bf16x8 cr = ((const bf16x8*)crow)[lane];
  bf16x8 ci = ((const bf16x8*)(crow + 512))[lane];

  for (int t = start; t < tend; ++t) {
    bf16x8 crn = cr, cin = ci;
    if (t + 1 < tend) {
      const bf16_t* nrow = c + ((size_t)b * S_DIM + (t + 1)) * D_DIM;
      crn = ((const bf16x8*)nrow)[lane];
      cin = ((const bf16x8*)(nrow + 512))[lane];
    }
    float nr[8], ni[8];
    float ss = 0.f;
#pragma unroll
    for (int j = 0; j < 8; ++j) {
      const float a  = zre[j], bb = zim[j];
      const float rr = fmaf(a, a, fmaf(-bb, bb, (float)cr[j]));
      const float ii = fmaf(2.f * a, bb, (float)ci[j]);
      nr[j] = rr; ni[j] = ii;
      ss = fmaf(rr, rr, ss);
      ss = fmaf(ii, ii, ss);
    }
#pragma unroll
    for (int off = 32; off; off >>= 1) ss += __shfl_xor(ss, off);
    const float nrm = sqrtf(ss + 1e-12f);
    const float sc  = 2.0f / fmaxf(nrm, 2.0f);
#pragma unroll
    for (int j = 0; j < 8; ++j) { zre[j] = nr[j] * sc; zim[j] = ni[j] * sc; }
    if (t >= t0) {
      bf16_t* yrow = y + ((size_t)b * S_DIM + t) * D_DIM;
      bf16x8 yr, yi;
#pragma unroll
      for (int j = 0; j < 8; ++j) { yr[j] = (bf16_t)zre[j]; yi[j] = (bf16_t)zim[j]; }
      ((bf16x8*)yrow)[lane]         = yr;
      ((bf16x8*)(yrow + 512))[lane] = yi;
    }
    cr = crn; ci = cin;
  }
}

extern "C" void kernel_launch(void* const* d_in, const int* in_sizes, int n_in,
                              void* d_out, int out_size, void* d_ws, size_t ws_size,
                              hipStream_t stream) {
  const float* x     = (const float*)d_in[0];
  const float* gamma = (const float*)d_in[1];
  const float* beta  = (const float*)d_in[2];
  const float* W_in  = (const float*)d_in[3];
  const float* b_in  = (const float*)d_in[4];
  const float* W_out = (const float*)d_in[5];
  const float* b_out = (const float*)d_in[6];
  float* out = (float*)d_out;

  char* ws = (char*)d_ws;
  bf16_t* hy  = (bf16_t*)(ws);                  // 32 MiB: h, later reused for y
  bf16_t* cbf = (bf16_t*)(ws + (32ull << 20));  // 32 MiB: c (bf16)
  bf16_t* wti = (bf16_t*)(ws + (64ull << 20));  // 2 MiB:  W_in^T bf16
  bf16_t* wto = (bf16_t*)(ws + (66ull << 20));  // 2 MiB:  W_out^T bf16

  transpose_kernel<<<dim3(32, 32), 256, 0, stream>>>(W_in, wti);
  transpose_kernel<<<dim3(32, 32), 256, 0, stream>>>(W_out, wto);
  ln_kernel<<<M_DIM, 64, 0, stream>>>(x, gamma, beta, hy);
  gemm_nt_kernel<0><<<256, 512, 0, stream>>>(hy, wti, b_in, nullptr, cbf);
  scan_kernel<<<dim3(S_DIM / CHUNK, B_DIM), 64, 0, stream>>>(cbf, hy);
  gemm_nt_kernel<1><<<256, 512, 0, stream>>>(hy, wto, b_out, x, out);
}

// Round 8
// 141.429 us; speedup vs baseline: 1.2657x; 1.2657x over previous
//
#include <hip/hip_runtime.h>

typedef __bf16 bf16_t;
typedef __bf16 bf16x8 __attribute__((ext_vector_type(8)));
typedef __bf16 bf16x4 __attribute__((ext_vector_type(4)));
typedef float  f32x4  __attribute__((ext_vector_type(4)));
typedef unsigned char u8;

#define B_DIM 4
#define S_DIM 4096
#define D_DIM 1024
#define M_DIM (B_DIM * S_DIM)   // 16384 rows

#define CHUNK 32   // scan output steps per block
#define WARM  16   // scan warm-up steps (0.28^16 ~ 1.5e-9)

__device__ __forceinline__ void g2l16(const void* g, void* l) {
  __builtin_amdgcn_global_load_lds(
      (const __attribute__((address_space(1))) void*)g,
      (__attribute__((address_space(3))) void*)l, 16, 0, 0);
}

// ---------------- LayerNorm fp32 -> fp8 e4m3, one wave per row ------------
__global__ __launch_bounds__(64) void ln_kernel(
    const float* __restrict__ x, const float* __restrict__ gamma,
    const float* __restrict__ beta, u8* __restrict__ h) {
  const int row  = blockIdx.x;
  const int lane = threadIdx.x;
  const float4* xr = (const float4*)(x + (size_t)row * D_DIM);
  float4 v[4];
  float s = 0.f, s2 = 0.f;
#pragma unroll
  for (int j = 0; j < 4; ++j) {
    v[j] = xr[j * 64 + lane];
    s += v[j].x + v[j].y + v[j].z + v[j].w;
    s2 = fmaf(v[j].x, v[j].x, s2);
    s2 = fmaf(v[j].y, v[j].y, s2);
    s2 = fmaf(v[j].z, v[j].z, s2);
    s2 = fmaf(v[j].w, v[j].w, s2);
  }
#pragma unroll
  for (int off = 32; off; off >>= 1) {
    s  += __shfl_xor(s, off);
    s2 += __shfl_xor(s2, off);
  }
  const float mu  = s * (1.f / (float)D_DIM);
  const float var = fmaf(-mu, mu, s2 * (1.f / (float)D_DIM));
  const float inv = rsqrtf(var + 1e-5f);
  int* hr = (int*)(h + (size_t)row * D_DIM);
#pragma unroll
  for (int j = 0; j < 4; ++j) {
    const float4 g4 = ((const float4*)gamma)[j * 64 + lane];
    const float4 b4 = ((const float4*)beta)[j * 64 + lane];
    const float o0 = fmaf((v[j].x - mu) * inv, g4.x, b4.x);
    const float o1 = fmaf((v[j].y - mu) * inv, g4.y, b4.y);
    const float o2 = fmaf((v[j].z - mu) * inv, g4.z, b4.z);
    const float o3 = fmaf((v[j].w - mu) * inv, g4.w, b4.w);
    int p = __builtin_amdgcn_cvt_pk_fp8_f32(o0, o1, 0, false);
    p = __builtin_amdgcn_cvt_pk_fp8_f32(o2, o3, p, true);
    hr[j * 64 + lane] = p;
  }
}

// ---- W [K][N] fp32 -> WT [N][K], bf16 variant (W_out) ----
__global__ __launch_bounds__(256) void transpose_bf16_kernel(
    const float* __restrict__ W, bf16_t* __restrict__ WT) {
  __shared__ float tile[32][33];
  const int tx = threadIdx.x & 31;
  const int ty = threadIdx.x >> 5;
  const int bn = blockIdx.x * 32;
  const int bk = blockIdx.y * 32;
#pragma unroll
  for (int i = 0; i < 32; i += 8)
    tile[ty + i][tx] = W[(size_t)(bk + ty + i) * D_DIM + bn + tx];
  __syncthreads();
#pragma unroll
  for (int i = 0; i < 32; i += 8)
    WT[(size_t)(bn + ty + i) * D_DIM + bk + tx] = (bf16_t)tile[tx][ty + i];
}

// ---- W [K][N] fp32 -> WT [N][K], fp8 e4m3 with x16 pre-scale (W_in) ----
__global__ __launch_bounds__(256) void transpose_fp8_kernel(
    const float* __restrict__ W, u8* __restrict__ WT) {
  __shared__ float tile[32][33];
  const int tx = threadIdx.x & 31;
  const int ty = threadIdx.x >> 5;
  const int bn = blockIdx.x * 32;
  const int bk = blockIdx.y * 32;
#pragma unroll
  for (int i = 0; i < 32; i += 8)
    tile[ty + i][tx] = W[(size_t)(bk + ty + i) * D_DIM + bn + tx];
  __syncthreads();
#pragma unroll
  for (int i = 0; i < 32; i += 8) {
    const int p =
        __builtin_amdgcn_cvt_pk_fp8_f32(16.f * tile[tx][ty + i], 0.f, 0, false);
    WT[(size_t)(bn + ty + i) * D_DIM + bk + tx] = (u8)(p & 0xff);
  }
}

// ====== fp8 NT GEMM, 256x128 tile, 8 waves, BK=64, dbuf-2 (GEMM1) =========
// c[M][N] = (A_f8[M][K] * BT_f8[N][K]^T)/16 + bias -> bf16
// LDS buffer (24 KB): A [256 rows][64B] @0 | B [128 rows][64B] @16384.
// Row = 64 k-bytes = 4 slots of 16; elem (row, k16-group g) at slot
// g ^ ((row>>1)&3). Fragment = ds_read_b64: addr = row*64 +
// (((kk*2 + (g>>1)) ^ ((row>>1)&3))<<4) + (g&1)*8  [hand-checked 0-conflict]
#define G1NT 16   // K / 64

__global__ __launch_bounds__(512, 4) void gemm_fp8_kernel(
    const u8* __restrict__ A, const u8* __restrict__ BT,
    const float* __restrict__ bias, bf16_t* __restrict__ Cout) {
  __shared__ __attribute__((aligned(16))) char lds[2][24576];
  const int tid  = threadIdx.x;
  const int lane = tid & 63;
  const int wave = tid >> 6;          // 0..7
  const int wr = wave >> 1;           // 0..3 (M quarter: 64 rows)
  const int wc = wave & 1;            // 0..1 (N half: 64 cols)
  const int bid = blockIdx.x;
  const int swz = (bid & 7) * 64 + (bid >> 3);   // 512 blocks, 8 XCDs
  const int m0 = (swz >> 3) * 256;
  const int n0 = (swz & 7) * 128;

  // staging: thread covers (row = tid>>2, phys slot = tid&3); logical
  // k16-group g = (tid&3)^((tid>>3)&3); source k-bytes g*16..+16
  const int gs = ((tid & 3) ^ ((tid >> 3) & 3)) << 4;
  const u8* srcA = A  + (size_t)(m0 + (tid >> 2)) * D_DIM + gs;
  const u8* srcB = BT + (size_t)(n0 + (tid >> 2)) * D_DIM + gs;
  const int l16 = tid * 16;

  // fragment addresses
  const int gg   = lane >> 4;
  const int arow = wr * 64 + (lane & 15);
  const int brow = wc * 64 + (lane & 15);
  const int aA0 = arow * 64 + ((((gg >> 1)) ^ ((arow >> 1) & 3)) << 4) + (gg & 1) * 8;
  const int bA0 = 16384 + brow * 64 +
                  ((((gg >> 1)) ^ ((brow >> 1) & 3)) << 4) + (gg & 1) * 8;

  f32x4 acc[4][4];
#pragma unroll
  for (int m = 0; m < 4; ++m)
#pragma unroll
    for (int n = 0; n < 4; ++n) acc[m][n] = (f32x4){0.f, 0.f, 0.f, 0.f};

#define STAGE(T)                                             \
  {                                                          \
    char* dst = lds[(T) & 1];                                \
    const size_t ko = (size_t)(T) * 64;                      \
    g2l16(srcA + ko, dst + l16);                             \
    g2l16(srcA + (size_t)128 * D_DIM + ko, dst + 8192 + l16);\
    g2l16(srcB + ko, dst + 16384 + l16);                     \
  }

  STAGE(0);
  for (int t = 0; t < G1NT; ++t) {
    __syncthreads();   // stage(t) DMA drained; buf[(t+1)&1] readers done
    const char* buf = lds[t & 1];
    long a0[4], b0[4], a1[4], b1[4];
#pragma unroll
    for (int m = 0; m < 4; ++m)
      a0[m] = *(const long*)(buf + ((aA0 + m * 1024)));
#pragma unroll
    for (int n = 0; n < 4; ++n)
      b0[n] = *(const long*)(buf + ((bA0 + n * 1024)));
#pragma unroll
    for (int m = 0; m < 4; ++m)
      a1[m] = *(const long*)(buf + ((aA0 + m * 1024) ^ 32));
#pragma unroll
    for (int n = 0; n < 4; ++n)
      b1[n] = *(const long*)(buf + ((bA0 + n * 1024) ^ 32));
    if (t + 1 < G1NT) STAGE(t + 1);
#pragma unroll
    for (int m = 0; m < 4; ++m)
#pragma unroll
      for (int n = 0; n < 4; ++n)
        acc[m][n] = __builtin_amdgcn_mfma_f32_16x16x32_fp8_fp8(
            a0[m], b0[n], acc[m][n], 0, 0, 0);
#pragma unroll
    for (int m = 0; m < 4; ++m)
#pragma unroll
      for (int n = 0; n < 4; ++n)
        acc[m][n] = __builtin_amdgcn_mfma_f32_16x16x32_fp8_fp8(
            a1[m], b1[n], acc[m][n], 0, 0, 0);
  }
#undef STAGE

  // epilogue: C/D layout col = lane&15, row = (lane>>4)*4 + r; un-scale /16
  const int rbase = m0 + wr * 64 + ((lane >> 4) << 2);
  const int cbase = n0 + wc * 64 + (lane & 15);
#pragma unroll
  for (int n = 0; n < 4; ++n) {
    const int col = cbase + n * 16;
    const float bn = bias[col];
#pragma unroll
    for (int m = 0; m < 4; ++m) {
      const int row = rbase + m * 16;
#pragma unroll
      for (int r = 0; r < 4; ++r)
        Cout[(size_t)(row + r) * D_DIM + col] =
            (bf16_t)fmaf(acc[m][n][r], 0.0625f, bn);
    }
  }
}

// == bf16 NT GEMM (GEMM2), 256x128 tile, ring-3 LDS, counted vmcnt =========
#define NTK 32
#define BUFSZ 24576
#define VMCNT(n) asm volatile("s_waitcnt vmcnt(" #n ")" ::: "memory")
#define DSR(d, a, off) \
  asm volatile("ds_read_b128 %0, %1 offset:" #off : "=v"(d) : "v"(a))

__global__ __launch_bounds__(512, 4) void gemm_bf16_kernel(
    const bf16_t* __restrict__ A, const bf16_t* __restrict__ BT,
    const float* __restrict__ bias, const float* __restrict__ xres,
    float* __restrict__ Cout) {
  __shared__ __attribute__((aligned(16))) char lds[3][BUFSZ];
  const int tid  = threadIdx.x;
  const int lane = tid & 63;
  const int wave = tid >> 6;
  const int wr = wave >> 1;            // 0..3
  const int wc = wave & 1;             // 0..1
  const int bid = blockIdx.x;
  const int swz = (bid & 7) * 64 + (bid >> 3);
  const int m0 = (swz >> 3) * 256;
  const int n0 = (swz & 7) * 128;

  const int ke = (((tid & 3) ^ ((tid >> 3) & 3)) << 3);
  const bf16_t* srcA = A  + (size_t)(m0 + (tid >> 2)) * D_DIM + ke;
  const bf16_t* srcB = BT + (size_t)(n0 + (tid >> 2)) * D_DIM + ke;
  const int l16 = tid * 16;

  const uint32_t lbase = (uint32_t)(uintptr_t)&lds[0][0];
  const int sw   = (((lane >> 4) ^ ((lane >> 1) & 3)) << 4);
  const uint32_t aoff = lbase + (uint32_t)((wr * 64 + (lane & 15)) * 64 + sw);
  const uint32_t boff = lbase + 16384u +
                        (uint32_t)((wc * 64 + (lane & 15)) * 64 + sw);

  f32x4 acc[4][4];
#pragma unroll
  for (int m = 0; m < 4; ++m)
#pragma unroll
    for (int n = 0; n < 4; ++n) acc[m][n] = (f32x4){0.f, 0.f, 0.f, 0.f};

#define STAGE(T, BI)                                          \
  {                                                           \
    char* dst = (char*)lds + (BI) * BUFSZ;                    \
    const size_t ko = (size_t)(T) * 32;                       \
    g2l16(srcA + ko, dst + l16);                              \
    g2l16(srcA + (size_t)128 * D_DIM + ko, dst + 8192 + l16); \
    g2l16(srcB + ko, dst + 16384 + l16);                      \
  }

#define STEP_BODY(CUR, DO_STAGE, T)                                 \
  {                                                                 \
    __builtin_amdgcn_s_barrier();                                   \
    const uint32_t bb = (uint32_t)(CUR) * BUFSZ;                    \
    bf16x8 af[4], bf[4];                                            \
    const uint32_t aA = aoff + bb;                                  \
    DSR(af[0], aA, 0);                                              \
    DSR(af[1], aA, 1024);                                           \
    DSR(af[2], aA, 2048);                                           \
    DSR(af[3], aA, 3072);                                           \
    const uint32_t bA = boff + bb;                                  \
    DSR(bf[0], bA, 0);                                              \
    DSR(bf[1], bA, 1024);                                           \
    DSR(bf[2], bA, 2048);                                           \
    DSR(bf[3], bA, 3072);                                           \
    if (DO_STAGE) { const int bi2 = (CUR) >= 1 ? (CUR) - 1 : (CUR) + 2; \
                    STAGE((T) + 2, bi2); }                          \
    asm volatile("s_waitcnt lgkmcnt(0)" ::: "memory");              \
    __builtin_amdgcn_sched_barrier(0);                              \
    _Pragma("unroll") for (int m = 0; m < 4; ++m)                   \
        _Pragma("unroll") for (int n = 0; n < 4; ++n)               \
            acc[m][n] = __builtin_amdgcn_mfma_f32_16x16x32_bf16(    \
                af[m], bf[n], acc[m][n], 0, 0, 0);                  \
  }

  STAGE(0, 0);
  STAGE(1, 1);
  int cur = 0;
  for (int t = 0; t < NTK - 1; ++t) {
    VMCNT(3);
    STEP_BODY(cur, t + 2 < NTK, t);
    cur = cur == 2 ? 0 : cur + 1;
  }
  VMCNT(0);
  STEP_BODY(cur, false, NTK - 1);

#undef STEP_BODY
#undef STAGE

  const int rbase = m0 + wr * 64 + ((lane >> 4) << 2);
  const int cbase = n0 + wc * 64 + (lane & 15);
#pragma unroll
  for (int n = 0; n < 4; ++n) {
    const int col = cbase + n * 16;
    const float bn = bias[col];
#pragma unroll
    for (int m = 0; m < 4; ++m) {
      const int row = rbase + m * 16;
#pragma unroll
      for (int r = 0; r < 4; ++r) {
        const size_t idx = (size_t)(row + r) * D_DIM + col;
        Cout[idx] = xres[idx] + acc[m][n][r] + bn;
      }
    }
  }
}

// ---------------- chunked chaotic scan, one wave per (batch, chunk) -------
__global__ __launch_bounds__(64) void scan_kernel(
    const bf16_t* __restrict__ c, bf16_t* __restrict__ y) {
  const int b     = blockIdx.y;
  const int chunk = blockIdx.x;
  const int t0    = chunk * CHUNK;
  const int start = (chunk == 0) ? 0 : t0 - WARM;
  const int tend  = t0 + CHUNK;
  const int lane  = threadIdx.x;

  float zre[8], zim[8];
#pragma unroll
  for (int j = 0; j < 8; ++j) { zre[j] = 0.f; zim[j] = 0.f; }

  const bf16_t* crow = c + ((size_t)b * S_DIM + start) * D_DIM;
  bf16x8 cr = ((const bf16x8*)crow)[lane];
  bf16x8 ci = ((const bf16x8*)(crow + 512))[lane];

  for (int t = start; t < tend; ++t) {
    bf16x8 crn = cr, cin = ci;
    if (t + 1 < tend) {
      const bf16_t* nrow = c + ((size_t)b * S_DIM + (t + 1)) * D_DIM;
      crn = ((const bf16x8*)nrow)[lane];
      cin = ((const bf16x8*)(nrow + 512))[lane];
    }
    float nr[8], ni[8];
    float ss = 0.f;
#pragma unroll
    for (int j = 0; j < 8; ++j) {
      const float a  = zre[j], bb = zim[j];
      const float rr = fmaf(a, a, fmaf(-bb, bb, (float)cr[j]));
      const float ii = fmaf(2.f * a, bb, (float)ci[j]);
      nr[j] = rr; ni[j] = ii;
      ss = fmaf(rr, rr, ss);
      ss = fmaf(ii, ii, ss);
    }
#pragma unroll
    for (int off = 32; off; off >>= 1) ss += __shfl_xor(ss, off);
    const float nrm = sqrtf(ss + 1e-12f);
    const float sc  = 2.0f / fmaxf(nrm, 2.0f);
#pragma unroll
    for (int j = 0; j < 8; ++j) { zre[j] = nr[j] * sc; zim[j] = ni[j] * sc; }
    if (t >= t0) {
      bf16_t* yrow = y + ((size_t)b * S_DIM + t) * D_DIM;
      bf16x8 yr, yi;
#pragma unroll
      for (int j = 0; j < 8; ++j) { yr[j] = (bf16_t)zre[j]; yi[j] = (bf16_t)zim[j]; }
      ((bf16x8*)yrow)[lane]         = yr;
      ((bf16x8*)(yrow + 512))[lane] = yi;
    }
    cr = crn; ci = cin;
  }
}

extern "C" void kernel_launch(void* const* d_in, const int* in_sizes, int n_in,
                              void* d_out, int out_size, void* d_ws, size_t ws_size,
                              hipStream_t stream) {
  const float* x     = (const float*)d_in[0];
  const float* gamma = (const float*)d_in[1];
  const float* beta  = (const float*)d_in[2];
  const float* W_in  = (const float*)d_in[3];
  const float* b_in  = (const float*)d_in[4];
  const float* W_out = (const float*)d_in[5];
  const float* b_out = (const float*)d_in[6];
  float* out = (float*)d_out;

  char* ws = (char*)d_ws;
  u8*     h8   = (u8*)(ws);                      // 16 MiB: h fp8 (dead after GEMM1)
  bf16_t* ybf  = (bf16_t*)(ws);                  // 32 MiB: y bf16 (overwrites h8)
  bf16_t* cbf  = (bf16_t*)(ws + (32ull << 20));  // 32 MiB: c bf16
  u8*     wti8 = (u8*)(ws + (64ull << 20));      // 1 MiB:  W_in^T fp8 (x16)
  bf16_t* wto  = (bf16_t*)(ws + (66ull << 20));  // 2 MiB:  W_out^T bf16

  transpose_fp8_kernel<<<dim3(32, 32), 256, 0, stream>>>(W_in, wti8);
  transpose_bf16_kernel<<<dim3(32, 32), 256, 0, stream>>>(W_out, wto);
  ln_kernel<<<M_DIM, 64, 0, stream>>>(x, gamma, beta, h8);
  gemm_fp8_kernel<<<512, 512, 0, stream>>>(h8, wti8, b_in, cbf);
  scan_kernel<<<dim3(S_DIM / CHUNK, B_DIM), 64, 0, stream>>>(cbf, ybf);
  gemm_bf16_kernel<<<512, 512, 0, stream>>>(ybf, wto, b_out, x, out);
}

// Round 10
// 132.188 us; speedup vs baseline: 1.3542x; 1.0699x over previous
//
#include <hip/hip_runtime.h>

typedef __bf16 bf16_t;
typedef __bf16 bf16x8 __attribute__((ext_vector_type(8)));
typedef __bf16 bf16x4 __attribute__((ext_vector_type(4)));
typedef float  f32x4  __attribute__((ext_vector_type(4)));
typedef unsigned char u8;
typedef unsigned long long u64;

#define B_DIM 4
#define S_DIM 4096
#define D_DIM 1024
#define M_DIM (B_DIM * S_DIM)   // 16384 rows

#define CHUNK 32   // scan output steps per block
#define WARM  16   // scan warm-up steps (0.28^16 ~ 1.5e-9)

__device__ __forceinline__ void g2l16(const void* g, void* l) {
  __builtin_amdgcn_global_load_lds(
      (const __attribute__((address_space(1))) void*)g,
      (__attribute__((address_space(3))) void*)l, 16, 0, 0);
}

// ---------------- LayerNorm fp32 -> fp8 e4m3, one wave per row ------------
__global__ __launch_bounds__(64) void ln_kernel(
    const float* __restrict__ x, const float* __restrict__ gamma,
    const float* __restrict__ beta, u8* __restrict__ h) {
  const int row  = blockIdx.x;
  const int lane = threadIdx.x;
  const float4* xr = (const float4*)(x + (size_t)row * D_DIM);
  float4 v[4];
  float s = 0.f, s2 = 0.f;
#pragma unroll
  for (int j = 0; j < 4; ++j) {
    v[j] = xr[j * 64 + lane];
    s += v[j].x + v[j].y + v[j].z + v[j].w;
    s2 = fmaf(v[j].x, v[j].x, s2);
    s2 = fmaf(v[j].y, v[j].y, s2);
    s2 = fmaf(v[j].z, v[j].z, s2);
    s2 = fmaf(v[j].w, v[j].w, s2);
  }
#pragma unroll
  for (int off = 32; off; off >>= 1) {
    s  += __shfl_xor(s, off);
    s2 += __shfl_xor(s2, off);
  }
  const float mu  = s * (1.f / (float)D_DIM);
  const float var = fmaf(-mu, mu, s2 * (1.f / (float)D_DIM));
  const float inv = rsqrtf(var + 1e-5f);
  int* hr = (int*)(h + (size_t)row * D_DIM);
#pragma unroll
  for (int j = 0; j < 4; ++j) {
    const float4 g4 = ((const float4*)gamma)[j * 64 + lane];
    const float4 b4 = ((const float4*)beta)[j * 64 + lane];
    const float o0 = fmaf((v[j].x - mu) * inv, g4.x, b4.x);
    const float o1 = fmaf((v[j].y - mu) * inv, g4.y, b4.y);
    const float o2 = fmaf((v[j].z - mu) * inv, g4.z, b4.z);
    const float o3 = fmaf((v[j].w - mu) * inv, g4.w, b4.w);
    int p = __builtin_amdgcn_cvt_pk_fp8_f32(o0, o1, 0, false);
    p = __builtin_amdgcn_cvt_pk_fp8_f32(o2, o3, p, true);
    hr[j * 64 + lane] = p;
  }
}

// ---- W [K][N] fp32 -> WT [N][K], fp8 e4m3 with x16 pre-scale -------------
__global__ __launch_bounds__(256) void transpose_fp8_kernel(
    const float* __restrict__ W, u8* __restrict__ WT) {
  __shared__ float tile[32][33];
  const int tx = threadIdx.x & 31;
  const int ty = threadIdx.x >> 5;
  const int bn = blockIdx.x * 32;
  const int bk = blockIdx.y * 32;
#pragma unroll
  for (int i = 0; i < 32; i += 8)
    tile[ty + i][tx] = W[(size_t)(bk + ty + i) * D_DIM + bn + tx];
  __syncthreads();
#pragma unroll
  for (int i = 0; i < 32; i += 8) {
    const int p =
        __builtin_amdgcn_cvt_pk_fp8_f32(16.f * tile[tx][ty + i], 0.f, 0, false);
    WT[(size_t)(bn + ty + i) * D_DIM + bk + tx] = (u8)(p & 0xff);
  }
}

// ====== fp8 NT GEMM, 256x128 tile, 8 waves, BK=64, dbuf-2 =================
// MODE 0 (GEMM1): h8 x (16*W_in)  -> c8 = fp8(acc/16 + bias)
// MODE 1 (GEMM2): (16*y8) x (16*W_out) -> f32 out = xres + acc/256 + bias
// LDS buffer (24 KB): A [256 rows][64B] @0 | B [128 rows][64B] @16384.
// elem (row, k16-group g) at slot g ^ ((row>>1)&3). Fragment = ds_read_b64.
#define G1NT 16   // K / 64

template <int MODE>
__global__ __launch_bounds__(512, 4) void gemm_fp8_kernel(
    const u8* __restrict__ A, const u8* __restrict__ BT,
    const float* __restrict__ bias, const float* __restrict__ xres,
    void* __restrict__ Cout) {
  __shared__ __attribute__((aligned(16))) char lds[2][24576];
  const int tid  = threadIdx.x;
  const int lane = tid & 63;
  const int wave = tid >> 6;          // 0..7
  const int wr = wave >> 1;           // 0..3 (M quarter: 64 rows)
  const int wc = wave & 1;            // 0..1 (N half: 64 cols)
  const int bid = blockIdx.x;
  const int swz = (bid & 7) * 64 + (bid >> 3);   // 512 blocks, 8 XCDs
  const int m0 = (swz >> 3) * 256;
  const int n0 = (swz & 7) * 128;

  // staging: thread covers (row = tid>>2, phys slot = tid&3); logical
  // k16-group g = (tid&3)^((tid>>3)&3); source k-bytes g*16..+16
  const int gs = ((tid & 3) ^ ((tid >> 3) & 3)) << 4;
  const u8* srcA = A  + (size_t)(m0 + (tid >> 2)) * D_DIM + gs;
  const u8* srcB = BT + (size_t)(n0 + (tid >> 2)) * D_DIM + gs;
  const int l16 = tid * 16;

  // fragment addresses
  const int gg   = lane >> 4;
  const int arow = wr * 64 + (lane & 15);
  const int brow = wc * 64 + (lane & 15);
  const int aA0 = arow * 64 + ((((gg >> 1)) ^ ((arow >> 1) & 3)) << 4) + (gg & 1) * 8;
  const int bA0 = 16384 + brow * 64 +
                  ((((gg >> 1)) ^ ((brow >> 1) & 3)) << 4) + (gg & 1) * 8;

  f32x4 acc[4][4];
#pragma unroll
  for (int m = 0; m < 4; ++m)
#pragma unroll
    for (int n = 0; n < 4; ++n) acc[m][n] = (f32x4){0.f, 0.f, 0.f, 0.f};

#define STAGE(T)                                             \
  {                                                          \
    char* dst = lds[(T) & 1];                                \
    const size_t ko = (size_t)(T) * 64;                      \
    g2l16(srcA + ko, dst + l16);                             \
    g2l16(srcA + (size_t)128 * D_DIM + ko, dst + 8192 + l16);\
    g2l16(srcB + ko, dst + 16384 + l16);                     \
  }

  STAGE(0);
  for (int t = 0; t < G1NT; ++t) {
    __syncthreads();   // stage(t) DMA drained; buf[(t+1)&1] readers done
    const char* buf = lds[t & 1];
    long a0[4], b0[4], a1[4], b1[4];
#pragma unroll
    for (int m = 0; m < 4; ++m)
      a0[m] = *(const long*)(buf + ((aA0 + m * 1024)));
#pragma unroll
    for (int n = 0; n < 4; ++n)
      b0[n] = *(const long*)(buf + ((bA0 + n * 1024)));
#pragma unroll
    for (int m = 0; m < 4; ++m)
      a1[m] = *(const long*)(buf + ((aA0 + m * 1024) ^ 32));
#pragma unroll
    for (int n = 0; n < 4; ++n)
      b1[n] = *(const long*)(buf + ((bA0 + n * 1024) ^ 32));
    if (t + 1 < G1NT) STAGE(t + 1);
#pragma unroll
    for (int m = 0; m < 4; ++m)
#pragma unroll
      for (int n = 0; n < 4; ++n)
        acc[m][n] = __builtin_amdgcn_mfma_f32_16x16x32_fp8_fp8(
            a0[m], b0[n], acc[m][n], 0, 0, 0);
#pragma unroll
    for (int m = 0; m < 4; ++m)
#pragma unroll
      for (int n = 0; n < 4; ++n)
        acc[m][n] = __builtin_amdgcn_mfma_f32_16x16x32_fp8_fp8(
            a1[m], b1[n], acc[m][n], 0, 0, 0);
  }
#undef STAGE

  // epilogue: C/D layout col = lane&15, row = (lane>>4)*4 + r
  const int rbase = m0 + wr * 64 + ((lane >> 4) << 2);
  const int cbase = n0 + wc * 64 + (lane & 15);
#pragma unroll
  for (int n = 0; n < 4; ++n) {
    const int col = cbase + n * 16;
    const float bn = bias[col];
#pragma unroll
    for (int m = 0; m < 4; ++m) {
      const int row = rbase + m * 16;
#pragma unroll
      for (int r = 0; r < 4; ++r) {
        const size_t idx = (size_t)(row + r) * D_DIM + col;
        if (MODE == 0) {
          const float cv = fmaf(acc[m][n][r], 0.0625f, bn);
          const int p = __builtin_amdgcn_cvt_pk_fp8_f32(cv, 0.f, 0, false);
          ((u8*)Cout)[idx] = (u8)(p & 0xff);
        } else {
          ((float*)Cout)[idx] =
              xres[idx] + fmaf(acc[m][n][r], 1.f / 256.f, bn);
        }
      }
    }
  }
}

// ------- chunked chaotic scan, fp8 c in / fp8 y out (x16 scale) -----------
// state: lane holds re pairs lane*8..+7 (bytes), im at +512
__global__ __launch_bounds__(64) void scan_kernel(
    const u8* __restrict__ c, u8* __restrict__ y) {
  const int b     = blockIdx.y;
  const int chunk = blockIdx.x;
  const int t0    = chunk * CHUNK;
  const int start = (chunk == 0) ? 0 : t0 - WARM;
  const int tend  = t0 + CHUNK;
  const int lane  = threadIdx.x;

  float zre[8], zim[8];
#pragma unroll
  for (int j = 0; j < 8; ++j) { zre[j] = 0.f; zim[j] = 0.f; }

  const u8* crow = c + ((size_t)b * S_DIM + start) * D_DIM;
  u64 cr = *(const u64*)(crow + lane * 8);
  u64 ci = *(const u64*)(crow + 512 + lane * 8);

  for (int t = start; t < tend; ++t) {
    u64 crn = cr, cin = ci;
    if (t + 1 < tend) {
      const u8* nrow = c + ((size_t)b * S_DIM + (t + 1)) * D_DIM;
      crn = *(const u64*)(nrow + lane * 8);
      cin = *(const u64*)(nrow + 512 + lane * 8);
    }
    float cre[8], cim[8];
    {
      const unsigned rl = (unsigned)cr, rh = (unsigned)(cr >> 32);
      const unsigned il = (unsigned)ci, ih = (unsigned)(ci >> 32);
      cre[0] = __builtin_amdgcn_cvt_f32_fp8(rl, 0);
      cre[1] = __builtin_amdgcn_cvt_f32_fp8(rl, 1);
      cre[2] = __builtin_amdgcn_cvt_f32_fp8(rl, 2);
      cre[3] = __builtin_amdgcn_cvt_f32_fp8(rl, 3);
      cre[4] = __builtin_amdgcn_cvt_f32_fp8(rh, 0);
      cre[5] = __builtin_amdgcn_cvt_f32_fp8(rh, 1);
      cre[6] = __builtin_amdgcn_cvt_f32_fp8(rh, 2);
      cre[7] = __builtin_amdgcn_cvt_f32_fp8(rh, 3);
      cim[0] = __builtin_amdgcn_cvt_f32_fp8(il, 0);
      cim[1] = __builtin_amdgcn_cvt_f32_fp8(il, 1);
      cim[2] = __builtin_amdgcn_cvt_f32_fp8(il, 2);
      cim[3] = __builtin_amdgcn_cvt_f32_fp8(il, 3);
      cim[4] = __builtin_amdgcn_cvt_f32_fp8(ih, 0);
      cim[5] = __builtin_amdgcn_cvt_f32_fp8(ih, 1);
      cim[6] = __builtin_amdgcn_cvt_f32_fp8(ih, 2);
      cim[7] = __builtin_amdgcn_cvt_f32_fp8(ih, 3);
    }
    float nr[8], ni[8];
    float ss = 0.f;
#pragma unroll
    for (int j = 0; j < 8; ++j) {
      const float a  = zre[j], bb = zim[j];
      const float rr = fmaf(a, a, fmaf(-bb, bb, cre[j]));
      const float ii = fmaf(2.f * a, bb, cim[j]);
      nr[j] = rr; ni[j] = ii;
      ss = fmaf(rr, rr, ss);
      ss = fmaf(ii, ii, ss);
    }
#pragma unroll
    for (int off = 32; off; off >>= 1) ss += __shfl_xor(ss, off);
    const float nrm = sqrtf(ss + 1e-12f);
    const float sc  = 2.0f / fmaxf(nrm, 2.0f);
#pragma unroll
    for (int j = 0; j < 8; ++j) { zre[j] = nr[j] * sc; zim[j] = ni[j] * sc; }
    if (t >= t0) {
      u8* yrow = y + ((size_t)b * S_DIM + t) * D_DIM;
      int pr0 = __builtin_amdgcn_cvt_pk_fp8_f32(16.f * zre[0], 16.f * zre[1], 0, false);
      pr0 = __builtin_amdgcn_cvt_pk_fp8_f32(16.f * zre[2], 16.f * zre[3], pr0, true);
      int pr1 = __builtin_amdgcn_cvt_pk_fp8_f32(16.f * zre[4], 16.f * zre[5], 0, false);
      pr1 = __builtin_amdgcn_cvt_pk_fp8_f32(16.f * zre[6], 16.f * zre[7], pr1, true);
      int pi0 = __builtin_amdgcn_cvt_pk_fp8_f32(16.f * zim[0], 16.f * zim[1], 0, false);
      pi0 = __builtin_amdgcn_cvt_pk_fp8_f32(16.f * zim[2], 16.f * zim[3], pi0, true);
      int pi1 = __builtin_amdgcn_cvt_pk_fp8_f32(16.f * zim[4], 16.f * zim[5], 0, false);
      pi1 = __builtin_amdgcn_cvt_pk_fp8_f32(16.f * zim[6], 16.f * zim[7], pi1, true);
      *(u64*)(yrow + lane * 8)       = ((u64)(unsigned)pr1 << 32) | (unsigned)pr0;
      *(u64*)(yrow + 512 + lane * 8) = ((u64)(unsigned)pi1 << 32) | (unsigned)pi0;
    }
    cr = crn; ci = cin;
  }
}

extern "C" void kernel_launch(void* const* d_in, const int* in_sizes, int n_in,
                              void* d_out, int out_size, void* d_ws, size_t ws_size,
                              hipStream_t stream) {
  const float* x     = (const float*)d_in[0];
  const float* gamma = (const float*)d_in[1];
  const float* beta  = (const float*)d_in[2];
  const float* W_in  = (const float*)d_in[3];
  const float* b_in  = (const float*)d_in[4];
  const float* W_out = (const float*)d_in[5];
  const float* b_out = (const float*)d_in[6];
  float* out = (float*)d_out;

  char* ws = (char*)d_ws;
  u8* hy8  = (u8*)(ws);                  // 16 MiB: h fp8, then y fp8 (alias)
  u8* c8   = (u8*)(ws + (16ull << 20));  // 16 MiB: c fp8
  u8* wti8 = (u8*)(ws + (64ull << 20));  // 1 MiB:  W_in^T  fp8 (x16)
  u8* wto8 = (u8*)(ws + (65ull << 20));  // 1 MiB:  W_out^T fp8 (x16)

  transpose_fp8_kernel<<<dim3(32, 32), 256, 0, stream>>>(W_in, wti8);
  transpose_fp8_kernel<<<dim3(32, 32), 256, 0, stream>>>(W_out, wto8);
  ln_kernel<<<M_DIM, 64, 0, stream>>>(x, gamma, beta, hy8);
  gemm_fp8_kernel<0><<<512, 512, 0, stream>>>(hy8, wti8, b_in, nullptr, c8);
  scan_kernel<<<dim3(S_DIM / CHUNK, B_DIM), 64, 0, stream>>>(c8, hy8);
  gemm_fp8_kernel<1><<<512, 512, 0, stream>>>(hy8, wto8, b_out, x, out);
}

// Round 11
// 125.462 us; speedup vs baseline: 1.4268x; 1.0536x over previous
//
#include <hip/hip_runtime.h>

typedef __bf16 bf16_t;
typedef float  f32x4  __attribute__((ext_vector_type(4)));
typedef long   longx2 __attribute__((ext_vector_type(2)));
typedef unsigned char u8;
typedef unsigned long long u64;

#define B_DIM 4
#define S_DIM 4096
#define D_DIM 1024
#define M_DIM (B_DIM * S_DIM)   // 16384 rows

#define CHUNK 32   // scan output steps per block
#define WARM  16   // scan warm-up steps

// pi-permutation within each 64-byte K-chunk: logical k = 64c+32h+8u+b
// stored at pos = 64c+16u+8h+b  (so a 16B unit = lane-group u's kk0+kk1 pair)
__device__ __forceinline__ int pperm(int k) {
  return (k & ~63) | (((k >> 3) & 3) << 4) | (((k >> 5) & 1) << 3) | (k & 7);
}

__device__ __forceinline__ void g2l16(const void* g, void* l) {
  __builtin_amdgcn_global_load_lds(
      (const __attribute__((address_space(1))) void*)g,
      (__attribute__((address_space(3))) void*)l, 16, 0, 0);
}

// -------- LayerNorm fp32 -> fp8 e4m3 (pi-permuted rows), wave per row -----
__global__ __launch_bounds__(64) void ln_kernel(
    const float* __restrict__ x, const float* __restrict__ gamma,
    const float* __restrict__ beta, u8* __restrict__ h) {
  const int row  = blockIdx.x;
  const int lane = threadIdx.x;
  const float4* xr = (const float4*)(x + (size_t)row * D_DIM);
  float4 v[4];
  float s = 0.f, s2 = 0.f;
#pragma unroll
  for (int j = 0; j < 4; ++j) {
    v[j] = xr[j * 64 + lane];
    s += v[j].x + v[j].y + v[j].z + v[j].w;
    s2 = fmaf(v[j].x, v[j].x, s2);
    s2 = fmaf(v[j].y, v[j].y, s2);
    s2 = fmaf(v[j].z, v[j].z, s2);
    s2 = fmaf(v[j].w, v[j].w, s2);
  }
#pragma unroll
  for (int off = 32; off; off >>= 1) {
    s  += __shfl_xor(s, off);
    s2 += __shfl_xor(s2, off);
  }
  const float mu  = s * (1.f / (float)D_DIM);
  const float var = fmaf(-mu, mu, s2 * (1.f / (float)D_DIM));
  const float inv = rsqrtf(var + 1e-5f);
  int* hr = (int*)(h + (size_t)row * D_DIM);
#pragma unroll
  for (int j = 0; j < 4; ++j) {
    const float4 g4 = ((const float4*)gamma)[j * 64 + lane];
    const float4 b4 = ((const float4*)beta)[j * 64 + lane];
    const float o0 = fmaf((v[j].x - mu) * inv, g4.x, b4.x);
    const float o1 = fmaf((v[j].y - mu) * inv, g4.y, b4.y);
    const float o2 = fmaf((v[j].z - mu) * inv, g4.z, b4.z);
    const float o3 = fmaf((v[j].w - mu) * inv, g4.w, b4.w);
    int p = __builtin_amdgcn_cvt_pk_fp8_f32(o0, o1, 0, false);
    p = __builtin_amdgcn_cvt_pk_fp8_f32(o2, o3, p, true);
    hr[pperm(j * 256 + lane * 4) >> 2] = p;
  }
}

// ---- W [K][N] fp32 -> WT [N][K] fp8 e4m3, x16 pre-scale, pi-permuted -----
__global__ __launch_bounds__(256) void transpose_fp8_kernel(
    const float* __restrict__ W, u8* __restrict__ WT) {
  __shared__ float tile[32][33];
  const int tx = threadIdx.x & 31;
  const int ty = threadIdx.x >> 5;
  const int bn = blockIdx.x * 32;
  const int bk = blockIdx.y * 32;
#pragma unroll
  for (int i = 0; i < 32; i += 8)
    tile[ty + i][tx] = W[(size_t)(bk + ty + i) * D_DIM + bn + tx];
  __syncthreads();
#pragma unroll
  for (int i = 0; i < 32; i += 8) {
    const int p =
        __builtin_amdgcn_cvt_pk_fp8_f32(16.f * tile[tx][ty + i], 0.f, 0, false);
    WT[(size_t)(bn + ty + i) * D_DIM + pperm(bk + tx)] = (u8)(p & 0xff);
  }
}

// ====== fp8 NT GEMM, 128x256 tile, BK=64, ring-3 LDS, counted vmcnt =======
// MODE 0 (GEMM1): h8 x (16*W_in)  -> c8 = fp8(acc/16 + bias)  [linear]
// MODE 1 (GEMM2): (16*y8) x (16*W_out) -> f32 out = xres + acc/256 + bias
// Inputs are pi-permuted. LDS buf (24KB): A [128 rows][64B] @0, B [256][64B]
// @8192. Stored-unit u placed at phys unit u ^ ((row>>1)&3); one b128 read
// = {kk0 8B, kk1 8B} for lane group g.  [R6 geometry: measured 0-conflict]
#define NTK 16        // K / 64
#define BUFSZ 24576

#define VMCNT(n) asm volatile("s_waitcnt vmcnt(" #n ")" ::: "memory")
#define DSRX(d, a, off) \
  asm volatile("ds_read_b128 %0, %1 offset:" #off : "=v"(d) : "v"(a))

template <int MODE>
__global__ __launch_bounds__(512, 4) void gemm_fp8_kernel(
    const u8* __restrict__ A, const u8* __restrict__ BT,
    const float* __restrict__ bias, const float* __restrict__ xres,
    void* __restrict__ Cout) {
  __shared__ __attribute__((aligned(16))) char lds[3][BUFSZ];
  const int tid  = threadIdx.x;
  const int lane = tid & 63;
  const int wave = tid >> 6;           // 0..7
  const int wr = wave >> 2;            // 0..1 (M half: 64 rows)
  const int wc = wave & 3;             // 0..3 (N quarter: 64 cols)
  const int bid = blockIdx.x;
  const int swz = (bid & 7) * 64 + (bid >> 3);   // 512 blocks, 8 XCDs
  const int m0 = (swz >> 2) * 128;     // 128 m-panels
  const int n0 = (swz & 3) * 256;      // 4 n-panels

  // convoy-breaking start stagger (hashed 0..7)
  const int dly = (int)((bid * 2654435761u) >> 29);
  for (int i = 0; i < dly; ++i) __builtin_amdgcn_s_sleep(1);

  // staging: thread t covers (row = t>>2, phys unit p = t&3); source stored
  // unit u = p ^ ((row>>1)&3) -> byte offset u*16 within permuted row
  const int us = (((tid & 3) ^ ((tid >> 3) & 3)) << 4);
  const u8* srcA = A  + (size_t)(m0 + (tid >> 2)) * D_DIM + us;
  const u8* srcB = BT + (size_t)(n0 + (tid >> 2)) * D_DIM + us;
  const int l16 = tid * 16;

  // fragment read bases: group g = lane>>4 at phys unit g ^ ((lane>>1)&3)
  const uint32_t lbase = (uint32_t)(uintptr_t)&lds[0][0];
  const int sw = (((lane >> 4) ^ ((lane >> 1) & 3)) << 4);
  const uint32_t aoff = lbase + (uint32_t)((wr * 64 + (lane & 15)) * 64 + sw);
  const uint32_t boff = lbase + 8192u +
                        (uint32_t)((wc * 64 + (lane & 15)) * 64 + sw);

  f32x4 acc[4][4];
#pragma unroll
  for (int m = 0; m < 4; ++m)
#pragma unroll
    for (int n = 0; n < 4; ++n) acc[m][n] = (f32x4){0.f, 0.f, 0.f, 0.f};

#define STAGE(T, BI)                                           \
  {                                                            \
    char* dst = (char*)lds + (BI) * BUFSZ;                     \
    const size_t ko = (size_t)(T) * 64;                        \
    g2l16(srcA + ko, dst + l16);                               \
    g2l16(srcB + ko, dst + 8192 + l16);                        \
    g2l16(srcB + (size_t)128 * D_DIM + ko, dst + 16384 + l16); \
  }

#define STEP_BODY(CUR, DO_STAGE, T)                                 \
  {                                                                 \
    __builtin_amdgcn_s_barrier();                                   \
    const uint32_t bb = (uint32_t)(CUR) * BUFSZ;                    \
    longx2 af[4], bf[4];                                            \
    const uint32_t aA = aoff + bb;                                  \
    DSRX(af[0], aA, 0);                                             \
    DSRX(af[1], aA, 1024);                                          \
    DSRX(af[2], aA, 2048);                                          \
    DSRX(af[3], aA, 3072);                                          \
    const uint32_t bA = boff + bb;                                  \
    DSRX(bf[0], bA, 0);                                             \
    DSRX(bf[1], bA, 1024);                                          \
    DSRX(bf[2], bA, 2048);                                          \
    DSRX(bf[3], bA, 3072);                                          \
    if (DO_STAGE) { const int bi2 = (CUR) >= 1 ? (CUR) - 1 : (CUR) + 2; \
                    STAGE((T) + 2, bi2); }                          \
    asm volatile("s_waitcnt lgkmcnt(0)" ::: "memory");              \
    __builtin_amdgcn_sched_barrier(0);                              \
    _Pragma("unroll") for (int m = 0; m < 4; ++m)                   \
        _Pragma("unroll") for (int n = 0; n < 4; ++n)               \
            acc[m][n] = __builtin_amdgcn_mfma_f32_16x16x32_fp8_fp8( \
                af[m][0], bf[n][0], acc[m][n], 0, 0, 0);            \
    _Pragma("unroll") for (int m = 0; m < 4; ++m)                   \
        _Pragma("unroll") for (int n = 0; n < 4; ++n)               \
            acc[m][n] = __builtin_amdgcn_mfma_f32_16x16x32_fp8_fp8( \
                af[m][1], bf[n][1], acc[m][n], 0, 0, 0);            \
  }

  STAGE(0, 0);
  STAGE(1, 1);
  int cur = 0;
  for (int t = 0; t < NTK - 1; ++t) {
    VMCNT(3);                 // stage(t) retired; barrier publishes it
    STEP_BODY(cur, t + 2 < NTK, t);
    cur = cur == 2 ? 0 : cur + 1;
  }
  VMCNT(0);
  STEP_BODY(cur, false, NTK - 1);

#undef STEP_BODY
#undef STAGE

  // epilogue: C/D layout col = lane&15, row = (lane>>4)*4 + r
  const int rbase = m0 + wr * 64 + ((lane >> 4) << 2);
  const int cbase = n0 + wc * 64 + (lane & 15);
#pragma unroll
  for (int n = 0; n < 4; ++n) {
    const int col = cbase + n * 16;
    const float bn = bias[col];
#pragma unroll
    for (int m = 0; m < 4; ++m) {
      const int row = rbase + m * 16;
#pragma unroll
      for (int r = 0; r < 4; ++r) {
        const size_t idx = (size_t)(row + r) * D_DIM + col;
        if (MODE == 0) {
          const float cv = fmaf(acc[m][n][r], 0.0625f, bn);
          const int p = __builtin_amdgcn_cvt_pk_fp8_f32(cv, 0.f, 0, false);
          ((u8*)Cout)[idx] = (u8)(p & 0xff);
        } else {
          ((float*)Cout)[idx] =
              xres[idx] + fmaf(acc[m][n][r], 1.f / 256.f, bn);
        }
      }
    }
  }
}

// --- chunked chaotic scan: c fp8 linear in, y fp8 x16 pi-permuted out -----
__global__ __launch_bounds__(64) void scan_kernel(
    const u8* __restrict__ c, u8* __restrict__ y) {
  const int b     = blockIdx.y;
  const int chunk = blockIdx.x;
  const int t0    = chunk * CHUNK;
  const int start = (chunk == 0) ? 0 : t0 - WARM;
  const int tend  = t0 + CHUNK;
  const int lane  = threadIdx.x;

  float zre[8], zim[8];
#pragma unroll
  for (int j = 0; j < 8; ++j) { zre[j] = 0.f; zim[j] = 0.f; }

  // permuted write offsets (b=0 within 8-blocks): re at d=lane*8, im +512
  const int dre = lane * 8;
  const int pre = (dre & ~63) | (((dre >> 3) & 3) << 4) | (((dre >> 5) & 1) << 3);
  const int pim = 512 + pre;

  const u8* crow = c + ((size_t)b * S_DIM + start) * D_DIM;
  u64 cr = *(const u64*)(crow + lane * 8);
  u64 ci = *(const u64*)(crow + 512 + lane * 8);

  for (int t = start; t < tend; ++t) {
    u64 crn = cr, cin = ci;
    if (t + 1 < tend) {
      const u8* nrow = c + ((size_t)b * S_DIM + (t + 1)) * D_DIM;
      crn = *(const u64*)(nrow + lane * 8);
      cin = *(const u64*)(nrow + 512 + lane * 8);
    }
    float cre[8], cim[8];
    {
      const unsigned rl = (unsigned)cr, rh = (unsigned)(cr >> 32);
      const unsigned il = (unsigned)ci, ih = (unsigned)(ci >> 32);
      cre[0] = __builtin_amdgcn_cvt_f32_fp8(rl, 0);
      cre[1] = __builtin_amdgcn_cvt_f32_fp8(rl, 1);
      cre[2] = __builtin_amdgcn_cvt_f32_fp8(rl, 2);
      cre[3] = __builtin_amdgcn_cvt_f32_fp8(rl, 3);
      cre[4] = __builtin_amdgcn_cvt_f32_fp8(rh, 0);
      cre[5] = __builtin_amdgcn_cvt_f32_fp8(rh, 1);
      cre[6] = __builtin_amdgcn_cvt_f32_fp8(rh, 2);
      cre[7] = __builtin_amdgcn_cvt_f32_fp8(rh, 3);
      cim[0] = __builtin_amdgcn_cvt_f32_fp8(il, 0);
      cim[1] = __builtin_amdgcn_cvt_f32_fp8(il, 1);
      cim[2] = __builtin_amdgcn_cvt_f32_fp8(il, 2);
      cim[3] = __builtin_amdgcn_cvt_f32_fp8(il, 3);
      cim[4] = __builtin_amdgcn_cvt_f32_fp8(ih, 0);
      cim[5] = __builtin_amdgcn_cvt_f32_fp8(ih, 1);
      cim[6] = __builtin_amdgcn_cvt_f32_fp8(ih, 2);
      cim[7] = __builtin_amdgcn_cvt_f32_fp8(ih, 3);
    }
    float nr[8], ni[8];
    float ss = 0.f;
#pragma unroll
    for (int j = 0; j < 8; ++j) {
      const float a  = zre[j], bb = zim[j];
      const float rr = fmaf(a, a, fmaf(-bb, bb, cre[j]));
      const float ii = fmaf(2.f * a, bb, cim[j]);
      nr[j] = rr; ni[j] = ii;
      ss = fmaf(rr, rr, ss);
      ss = fmaf(ii, ii, ss);
    }
#pragma unroll
    for (int off = 32; off; off >>= 1) ss += __shfl_xor(ss, off);
    const float nrm = sqrtf(ss + 1e-12f);
    const float sc  = 2.0f / fmaxf(nrm, 2.0f);
#pragma unroll
    for (int j = 0; j < 8; ++j) { zre[j] = nr[j] * sc; zim[j] = ni[j] * sc; }
    if (t >= t0) {
      u8* yrow = y + ((size_t)b * S_DIM + t) * D_DIM;
      int pr0 = __builtin_amdgcn_cvt_pk_fp8_f32(16.f * zre[0], 16.f * zre[1], 0, false);
      pr0 = __builtin_amdgcn_cvt_pk_fp8_f32(16.f * zre[2], 16.f * zre[3], pr0, true);
      int pr1 = __builtin_amdgcn_cvt_pk_fp8_f32(16.f * zre[4], 16.f * zre[5], 0, false);
      pr1 = __builtin_amdgcn_cvt_pk_fp8_f32(16.f * zre[6], 16.f * zre[7], pr1, true);
      int pi0 = __builtin_amdgcn_cvt_pk_fp8_f32(16.f * zim[0], 16.f * zim[1], 0, false);
      pi0 = __builtin_amdgcn_cvt_pk_fp8_f32(16.f * zim[2], 16.f * zim[3], pi0, true);
      int pi1 = __builtin_amdgcn_cvt_pk_fp8_f32(16.f * zim[4], 16.f * zim[5], 0, false);
      pi1 = __builtin_amdgcn_cvt_pk_fp8_f32(16.f * zim[6], 16.f * zim[7], pi1, true);
      *(u64*)(yrow + pre) = ((u64)(unsigned)pr1 << 32) | (unsigned)pr0;
      *(u64*)(yrow + pim) = ((u64)(unsigned)pi1 << 32) | (unsigned)pi0;
    }
    cr = crn; ci = cin;
  }
}

extern "C" void kernel_launch(void* const* d_in, const int* in_sizes, int n_in,
                              void* d_out, int out_size, void* d_ws, size_t ws_size,
                              hipStream_t stream) {
  const float* x     = (const float*)d_in[0];
  const float* gamma = (const float*)d_in[1];
  const float* beta  = (const float*)d_in[2];
  const float* W_in  = (const float*)d_in[3];
  const float* b_in  = (const float*)d_in[4];
  const float* W_out = (const float*)d_in[5];
  const float* b_out = (const float*)d_in[6];
  float* out = (float*)d_out;

  char* ws = (char*)d_ws;
  u8* hy8  = (u8*)(ws);                  // 16 MiB: h fp8, then y fp8 (alias)
  u8* c8   = (u8*)(ws + (16ull << 20));  // 16 MiB: c fp8 (linear)
  u8* wti8 = (u8*)(ws + (64ull << 20));  // 1 MiB:  W_in^T  fp8 (x16, perm)
  u8* wto8 = (u8*)(ws + (65ull << 20));  // 1 MiB:  W_out^T fp8 (x16, perm)

  transpose_fp8_kernel<<<dim3(32, 32), 256, 0, stream>>>(W_in, wti8);
  transpose_fp8_kernel<<<dim3(32, 32), 256, 0, stream>>>(W_out, wto8);
  ln_kernel<<<M_DIM, 64, 0, stream>>>(x, gamma, beta, hy8);
  gemm_fp8_kernel<0><<<512, 512, 0, stream>>>(hy8, wti8, b_in, nullptr, c8);
  scan_kernel<<<dim3(S_DIM / CHUNK, B_DIM), 64, 0, stream>>>(c8, hy8);
  gemm_fp8_kernel<1><<<512, 512, 0, stream>>>(hy8, wto8, b_out, x, out);
}